// Round 6
// baseline (540.951 us; speedup 1.0000x reference)
//
#include <hip/hip_runtime.h>
#include <hip/hip_bf16.h>
#include <cstddef>

#define T_TOK 2048
#define H_DIM 768
#define NEXP 16
#define KSEL 4
#define I_DIM 768
#define TWO_I 1536
#define NSLOT (T_TOK*KSEL)
#define ALPHA 1.702f
#define LIMIT 7.0f
#define EPS_RMS 1e-5f

typedef _Float16 f16;
typedef _Float16 half8 __attribute__((ext_vector_type(8)));
typedef float f32x4 __attribute__((ext_vector_type(4)));

// ---------------- Kernel 1: RMSNorm + router (fp32) + residual init ----------------
// t_norm stored as split fp16 (hi + residual lo) for the MFMA experts path.
__global__ __launch_bounds__(256) void k_rms_router(
    const float* __restrict__ x, const float* __restrict__ scale,
    const float* __restrict__ gw, const float* __restrict__ gb,
    f16* __restrict__ th, f16* __restrict__ tl, float* __restrict__ out,
    int* __restrict__ topk_idx, float* __restrict__ topk_w,
    int* __restrict__ counts)
{
    int t = blockIdx.x;
    int tid = threadIdx.x;
    int lane = tid & 63, wid = tid >> 6;
    __shared__ float ts[H_DIM];
    __shared__ float red[8];
    __shared__ float logits[NEXP];

    const float* xr = x + (size_t)t * H_DIM;
    float v0 = xr[tid], v1 = xr[tid + 256], v2 = xr[tid + 512];
    float ss = v0*v0 + v1*v1 + v2*v2;
    #pragma unroll
    for (int m = 32; m >= 1; m >>= 1) ss += __shfl_xor(ss, m, 64);
    if (lane == 0) red[wid] = ss;
    __syncthreads();
    if (tid == 0) {
        float tot = red[0] + red[1] + red[2] + red[3];
        red[4] = rsqrtf(tot / (float)H_DIM + EPS_RMS);
    }
    __syncthreads();
    float rinv = red[4];
    float t0 = v0 * rinv * scale[tid];
    float t1 = v1 * rinv * scale[tid + 256];
    float t2 = v2 * rinv * scale[tid + 512];
    ts[tid] = t0; ts[tid + 256] = t1; ts[tid + 512] = t2;
    // split fp16 store of t
    size_t base = (size_t)t * H_DIM;
    f16 h0 = (f16)t0, h1 = (f16)t1, h2 = (f16)t2;
    th[base + tid] = h0;       tl[base + tid]       = (f16)(t0 - (float)h0);
    th[base + tid + 256] = h1; tl[base + tid + 256] = (f16)(t1 - (float)h1);
    th[base + tid + 512] = h2; tl[base + tid + 512] = (f16)(t2 - (float)h2);
    // residual init: out = x
    float* op = out + base;
    op[tid] = v0; op[tid + 256] = v1; op[tid + 512] = v2;
    __syncthreads();

    // gate logits: wave wid handles experts 4*wid .. 4*wid+3 (fp32, exact)
    #pragma unroll
    for (int ee = 0; ee < 4; ++ee) {
        int e = wid * 4 + ee;
        const float* g = gw + (size_t)e * H_DIM;
        float p = 0.f;
        for (int i = lane; i < H_DIM; i += 64) p += ts[i] * g[i];
        #pragma unroll
        for (int m = 32; m >= 1; m >>= 1) p += __shfl_xor(p, m, 64);
        if (lane == 0) logits[e] = p + gb[e];
    }
    __syncthreads();

    if (tid == 0) {
        float lg[NEXP];
        #pragma unroll
        for (int e = 0; e < NEXP; ++e) lg[e] = logits[e];
        float vals[KSEL]; int idx[KSEL];
        #pragma unroll
        for (int k = 0; k < KSEL; ++k) {
            float best = -1e30f; int bi = 0;
            for (int e = 0; e < NEXP; ++e)
                if (lg[e] > best) { best = lg[e]; bi = e; }   // strict > => lowest index on ties (lax.top_k)
            vals[k] = best; idx[k] = bi; lg[bi] = -1e30f;
        }
        float mx = vals[0], sum = 0.f, ex[KSEL];
        #pragma unroll
        for (int k = 0; k < KSEL; ++k) { ex[k] = expf(vals[k] - mx); sum += ex[k]; }
        float inv = 1.f / sum;
        #pragma unroll
        for (int k = 0; k < KSEL; ++k) {
            topk_idx[t * KSEL + k] = idx[k];
            topk_w[t * KSEL + k] = ex[k] * inv;   // softmax/K * K cancels
            atomicAdd(&counts[idx[k]], 1);
        }
    }
}

// ---------------- Kernel 2: prefix scan over 16 expert counts ----------------
__global__ void k_scan(const int* __restrict__ counts, int* __restrict__ offsets)
{
    if (threadIdx.x == 0) {
        int acc = 0;
        for (int e = 0; e < NEXP; ++e) { offsets[e] = acc; acc += counts[e]; }
        offsets[NEXP] = acc;
    }
}

// ---------------- Kernel 3: scatter tokens into compact per-expert lists ----------------
__global__ __launch_bounds__(256) void k_place(
    const int* __restrict__ topk_idx, const float* __restrict__ topk_w,
    const int* __restrict__ offsets, int* __restrict__ cursor,
    int* __restrict__ expert_tokens, float* __restrict__ expert_wts)
{
    int t = blockIdx.x * 256 + threadIdx.x;
    if (t >= T_TOK) return;
    #pragma unroll
    for (int k = 0; k < KSEL; ++k) {
        int e = topk_idx[t * KSEL + k];
        int pos = atomicAdd(&cursor[e], 1);
        int slot = offsets[e] + pos;
        expert_tokens[slot] = t;
        expert_wts[slot] = topk_w[t * KSEL + k];
    }
}

// ---------------- Kernel 4: GEMM1 (H->2I) split-fp16 MFMA + bias + SwiGLU ----------------
// grid (I/64, T/64, E), block 256 (4 waves). Block tile 64 rows x (64 glu + 64 lin) cols.
// Wave w computes rows [w*16, w*16+16). Split-3 MFMA: Ah*Bh + Ah*Bl + Al*Bh (fp32 acc).
__global__ __launch_bounds__(256) void k_gemm1(
    const f16* __restrict__ th, const f16* __restrict__ tl,
    const float* __restrict__ w1, const float* __restrict__ b1,
    const int* __restrict__ expert_tokens, const int* __restrict__ offsets,
    f16* __restrict__ h_h, f16* __restrict__ h_l)
{
    int e = blockIdx.z;
    int beg = offsets[e];
    int cnt = offsets[e + 1] - beg;
    int m0 = blockIdx.y * 64;
    if (m0 >= cnt) return;
    int n0 = blockIdx.x * 64;
    int rows = min(64, cnt - m0);

    __shared__ f16 A_h[64][40];   // [row][k], 80B rows: 16B-aligned b128 frags, 8-way floor banks
    __shared__ f16 A_l[64][40];
    __shared__ f16 Bg_h[64][40];  // transposed: [n][k]
    __shared__ f16 Bg_l[64][40];
    __shared__ f16 Bn_h[64][40];
    __shared__ f16 Bn_l[64][40];
    __shared__ int toks[64];

    int tid = threadIdx.x;
    int w = tid >> 6, lane = tid & 63;
    if (tid < 64) toks[tid] = (tid < rows) ? expert_tokens[beg + m0 + tid] : -1;
    __syncthreads();

    // staging indices
    int arow = tid >> 2, ach = tid & 3;                 // A: 64 rows x 4 chunks of 8 k
    int tokA = toks[arow];
    // compute indices
    int fr = lane & 15, fg = lane >> 4;                 // frag row/col, k-group
    int r0 = w * 16;

    f32x4 zero4 = {0.f, 0.f, 0.f, 0.f};
    f32x4 accg[4], accn[4];
    #pragma unroll
    for (int s = 0; s < 4; ++s) { accg[s] = zero4; accn[s] = zero4; }

    for (int kk = 0; kk < H_DIM; kk += 32) {
        // ---- load A (gathered token rows, split fp16 from th/tl) ----
        half8 va_h, va_l;
        if (tokA >= 0) {
            size_t off = (size_t)tokA * H_DIM + kk + ach * 8;
            va_h = *(const half8*)(th + off);
            va_l = *(const half8*)(tl + off);
        } else {
            #pragma unroll
            for (int j = 0; j < 8; ++j) { va_h[j] = (f16)0.f; va_l[j] = (f16)0.f; }
        }
        // ---- load B: wave w stages k-rows w*8..w*8+7; lane = n. register transpose + split ----
        const float* wrow = w1 + ((size_t)(e * H_DIM + kk + w * 8)) * TWO_I + n0 + lane;
        half8 vgh, vgl, vnh, vnl;
        #pragma unroll
        for (int j = 0; j < 8; ++j) {
            float g  = wrow[(size_t)j * TWO_I];
            float li = wrow[(size_t)j * TWO_I + I_DIM];
            f16 gh = (f16)g;  vgh[j] = gh; vgl[j] = (f16)(g  - (float)gh);
            f16 lh = (f16)li; vnh[j] = lh; vnl[j] = (f16)(li - (float)lh);
        }
        __syncthreads();   // previous tile consumed
        *(half8*)&A_h[arow][ach * 8] = va_h;
        *(half8*)&A_l[arow][ach * 8] = va_l;
        *(half8*)&Bg_h[lane][w * 8] = vgh;
        *(half8*)&Bg_l[lane][w * 8] = vgl;
        *(half8*)&Bn_h[lane][w * 8] = vnh;
        *(half8*)&Bn_l[lane][w * 8] = vnl;
        __syncthreads();
        // ---- compute: A-frag (this wave's 16 rows) x 4 col-subtiles x (glu, lin) ----
        half8 ah  = *(const half8*)&A_h[r0 + fr][fg * 8];
        half8 al2 = *(const half8*)&A_l[r0 + fr][fg * 8];
        #pragma unroll
        for (int s = 0; s < 4; ++s) {
            int nb = s * 16 + fr;
            half8 bgh = *(const half8*)&Bg_h[nb][fg * 8];
            half8 bgl = *(const half8*)&Bg_l[nb][fg * 8];
            accg[s] = __builtin_amdgcn_mfma_f32_16x16x32_f16(ah,  bgh, accg[s], 0, 0, 0);
            accg[s] = __builtin_amdgcn_mfma_f32_16x16x32_f16(ah,  bgl, accg[s], 0, 0, 0);
            accg[s] = __builtin_amdgcn_mfma_f32_16x16x32_f16(al2, bgh, accg[s], 0, 0, 0);
            half8 bnh = *(const half8*)&Bn_h[nb][fg * 8];
            half8 bnl = *(const half8*)&Bn_l[nb][fg * 8];
            accn[s] = __builtin_amdgcn_mfma_f32_16x16x32_f16(ah,  bnh, accn[s], 0, 0, 0);
            accn[s] = __builtin_amdgcn_mfma_f32_16x16x32_f16(ah,  bnl, accn[s], 0, 0, 0);
            accn[s] = __builtin_amdgcn_mfma_f32_16x16x32_f16(al2, bnh, accn[s], 0, 0, 0);
        }
    }

    // ---- epilogue: bias + SwiGLU, split-fp16 store of h ----
    // C/D mapping (m89-verified): col = lane&15, row_in_16tile = (lane>>4)*4 + reg
    const float* b1p = b1 + (size_t)e * TWO_I + n0;
    #pragma unroll
    for (int s = 0; s < 4; ++s) {
        #pragma unroll
        for (int r4 = 0; r4 < 4; ++r4) {
            int rt = r0 + fg * 4 + r4;          // row within 64-row block tile
            if (rt >= rows) continue;
            int slot = beg + m0 + rt;
            int c = s * 16 + fr;
            float hg = accg[s][r4] + b1p[c];
            float hl2 = accn[s][r4] + b1p[I_DIM + c];
            hg = fminf(hg, LIMIT);
            hl2 = fminf(fmaxf(hl2, -LIMIT), LIMIT);
            float sg = 1.f / (1.f + expf(-ALPHA * hg));
            float hv = hg * sg * (hl2 + 1.f);
            f16 hh = (f16)hv;
            size_t off = (size_t)slot * I_DIM + n0 + c;
            h_h[off] = hh;
            h_l[off] = (f16)(hv - (float)hh);
        }
    }
}

// ---------------- Kernel 5: GEMM2 (I->H) split-fp16 MFMA + bias + weighted combine ----------------
__global__ __launch_bounds__(256) void k_gemm2(
    const f16* __restrict__ h_h, const f16* __restrict__ h_l,
    const float* __restrict__ w2, const float* __restrict__ b2,
    const int* __restrict__ expert_tokens, const float* __restrict__ expert_wts,
    const int* __restrict__ offsets, float* __restrict__ out)
{
    int e = blockIdx.z;
    int beg = offsets[e];
    int cnt = offsets[e + 1] - beg;
    int m0 = blockIdx.y * 64;
    if (m0 >= cnt) return;
    int n0 = blockIdx.x * 64;
    int rows = min(64, cnt - m0);

    __shared__ f16 A_h[64][40];
    __shared__ f16 A_l[64][40];
    __shared__ f16 B_h[64][40];   // transposed [n][k]
    __shared__ f16 B_l[64][40];
    __shared__ int   toks[64];
    __shared__ float wts[64];

    int tid = threadIdx.x;
    int w = tid >> 6, lane = tid & 63;
    if (tid < 64) {
        bool ok = tid < rows;
        toks[tid] = ok ? expert_tokens[beg + m0 + tid] : -1;
        wts[tid]  = ok ? expert_wts[beg + m0 + tid] : 0.f;
    }
    __syncthreads();

    int arow = tid >> 2, ach = tid & 3;
    bool aok = arow < rows;
    int fr = lane & 15, fg = lane >> 4;
    int r0 = w * 16;

    f32x4 zero4 = {0.f, 0.f, 0.f, 0.f};
    f32x4 acc[4];
    #pragma unroll
    for (int s = 0; s < 4; ++s) acc[s] = zero4;

    for (int kk = 0; kk < I_DIM; kk += 32) {
        half8 va_h, va_l;
        if (aok) {
            size_t off = (size_t)(beg + m0 + arow) * I_DIM + kk + ach * 8;
            va_h = *(const half8*)(h_h + off);
            va_l = *(const half8*)(h_l + off);
        } else {
            #pragma unroll
            for (int j = 0; j < 8; ++j) { va_h[j] = (f16)0.f; va_l[j] = (f16)0.f; }
        }
        const float* wrow = w2 + ((size_t)(e * I_DIM + kk + w * 8)) * H_DIM + n0 + lane;
        half8 vbh, vbl;
        #pragma unroll
        for (int j = 0; j < 8; ++j) {
            float b = wrow[(size_t)j * H_DIM];
            f16 bh = (f16)b; vbh[j] = bh; vbl[j] = (f16)(b - (float)bh);
        }
        __syncthreads();
        *(half8*)&A_h[arow][ach * 8] = va_h;
        *(half8*)&A_l[arow][ach * 8] = va_l;
        *(half8*)&B_h[lane][w * 8] = vbh;
        *(half8*)&B_l[lane][w * 8] = vbl;
        __syncthreads();
        half8 ah  = *(const half8*)&A_h[r0 + fr][fg * 8];
        half8 al2 = *(const half8*)&A_l[r0 + fr][fg * 8];
        #pragma unroll
        for (int s = 0; s < 4; ++s) {
            int nb = s * 16 + fr;
            half8 bh = *(const half8*)&B_h[nb][fg * 8];
            half8 bl = *(const half8*)&B_l[nb][fg * 8];
            acc[s] = __builtin_amdgcn_mfma_f32_16x16x32_f16(ah,  bh, acc[s], 0, 0, 0);
            acc[s] = __builtin_amdgcn_mfma_f32_16x16x32_f16(ah,  bl, acc[s], 0, 0, 0);
            acc[s] = __builtin_amdgcn_mfma_f32_16x16x32_f16(al2, bh, acc[s], 0, 0, 0);
        }
    }

    const float* b2p = b2 + (size_t)e * H_DIM + n0;
    #pragma unroll
    for (int s = 0; s < 4; ++s) {
        #pragma unroll
        for (int r4 = 0; r4 < 4; ++r4) {
            int rt = r0 + fg * 4 + r4;
            if (rt >= rows) continue;
            int tok = toks[rt];
            float wgt = wts[rt];
            int c = s * 16 + fr;
            atomicAdd(out + (size_t)tok * H_DIM + n0 + c, wgt * (acc[s][r4] + b2p[c]));
        }
    }
}

// ---------------- launch ----------------
extern "C" void kernel_launch(void* const* d_in, const int* in_sizes, int n_in,
                              void* d_out, int out_size, void* d_ws, size_t ws_size,
                              hipStream_t stream)
{
    const float* x     = (const float*)d_in[0];
    const float* scale = (const float*)d_in[1];
    const float* gw    = (const float*)d_in[2];
    const float* gb    = (const float*)d_in[3];
    const float* w1    = (const float*)d_in[4];
    const float* b1    = (const float*)d_in[5];
    const float* w2    = (const float*)d_in[6];
    const float* b2    = (const float*)d_in[7];
    float* out = (float*)d_out;

    char* ws = (char*)d_ws;
    f16* th  = (f16*)ws;                                   ws += (size_t)T_TOK * H_DIM * 2;
    f16* tl  = (f16*)ws;                                   ws += (size_t)T_TOK * H_DIM * 2;
    f16* h_h = (f16*)ws;                                   ws += (size_t)NSLOT * I_DIM * 2;
    f16* h_l = (f16*)ws;                                   ws += (size_t)NSLOT * I_DIM * 2;
    float* topk_w        = (float*)ws;                     ws += NSLOT * 4;
    float* expert_wts    = (float*)ws;                     ws += NSLOT * 4;
    int*   topk_idx      = (int*)ws;                       ws += NSLOT * 4;
    int*   expert_tokens = (int*)ws;                       ws += NSLOT * 4;
    int*   counts        = (int*)ws;                       ws += NEXP * 4;
    int*   cursor        = (int*)ws;                       ws += NEXP * 4;
    int*   offsets       = (int*)ws;

    hipMemsetAsync(counts, 0, sizeof(int) * 2 * NEXP, stream);  // counts + cursor

    hipLaunchKernelGGL(k_rms_router, dim3(T_TOK), dim3(256), 0, stream,
                       x, scale, gw, gb, th, tl, out, topk_idx, topk_w, counts);
    hipLaunchKernelGGL(k_scan, dim3(1), dim3(64), 0, stream, counts, offsets);
    hipLaunchKernelGGL(k_place, dim3(T_TOK / 256), dim3(256), 0, stream,
                       topk_idx, topk_w, offsets, cursor, expert_tokens, expert_wts);
    hipLaunchKernelGGL(k_gemm1, dim3(I_DIM / 64, T_TOK / 64, NEXP), dim3(256), 0, stream,
                       th, tl, w1, b1, expert_tokens, offsets, h_h, h_l);
    hipLaunchKernelGGL(k_gemm2, dim3(H_DIM / 64, T_TOK / 64, NEXP), dim3(256), 0, stream,
                       h_h, h_l, w2, b2, expert_tokens, expert_wts, offsets, out);
}

// Round 7
// 470.936 us; speedup vs baseline: 1.1487x; 1.1487x over previous
//
#include <hip/hip_runtime.h>
#include <hip/hip_bf16.h>
#include <cstddef>

#define T_TOK 2048
#define H_DIM 768
#define NEXP 16
#define KSEL 4
#define I_DIM 768
#define TWO_I 1536
#define NSLOT (T_TOK*KSEL)
#define ALPHA 1.702f
#define LIMIT 7.0f
#define EPS_RMS 1e-5f
#define BM 128

typedef _Float16 f16;
typedef _Float16 half8 __attribute__((ext_vector_type(8)));
typedef float f32x4 __attribute__((ext_vector_type(4)));

// ---------------- Kernel 1: RMSNorm + router (fp32) + residual init ----------------
__global__ __launch_bounds__(256) void k_rms_router(
    const float* __restrict__ x, const float* __restrict__ scale,
    const float* __restrict__ gw, const float* __restrict__ gb,
    f16* __restrict__ th, f16* __restrict__ tl, float* __restrict__ out,
    int* __restrict__ topk_idx, float* __restrict__ topk_w,
    int* __restrict__ counts)
{
    int t = blockIdx.x;
    int tid = threadIdx.x;
    int lane = tid & 63, wid = tid >> 6;
    __shared__ float ts[H_DIM];
    __shared__ float red[8];
    __shared__ float logits[NEXP];

    const float* xr = x + (size_t)t * H_DIM;
    float v0 = xr[tid], v1 = xr[tid + 256], v2 = xr[tid + 512];
    float ss = v0*v0 + v1*v1 + v2*v2;
    #pragma unroll
    for (int m = 32; m >= 1; m >>= 1) ss += __shfl_xor(ss, m, 64);
    if (lane == 0) red[wid] = ss;
    __syncthreads();
    if (tid == 0) {
        float tot = red[0] + red[1] + red[2] + red[3];
        red[4] = rsqrtf(tot / (float)H_DIM + EPS_RMS);
    }
    __syncthreads();
    float rinv = red[4];
    float t0 = v0 * rinv * scale[tid];
    float t1 = v1 * rinv * scale[tid + 256];
    float t2 = v2 * rinv * scale[tid + 512];
    ts[tid] = t0; ts[tid + 256] = t1; ts[tid + 512] = t2;
    size_t base = (size_t)t * H_DIM;
    f16 h0 = (f16)t0, h1 = (f16)t1, h2 = (f16)t2;
    th[base + tid] = h0;       tl[base + tid]       = (f16)(t0 - (float)h0);
    th[base + tid + 256] = h1; tl[base + tid + 256] = (f16)(t1 - (float)h1);
    th[base + tid + 512] = h2; tl[base + tid + 512] = (f16)(t2 - (float)h2);
    float* op = out + base;
    op[tid] = v0; op[tid + 256] = v1; op[tid + 512] = v2;
    __syncthreads();

    #pragma unroll
    for (int ee = 0; ee < 4; ++ee) {
        int e = wid * 4 + ee;
        const float* g = gw + (size_t)e * H_DIM;
        float p = 0.f;
        for (int i = lane; i < H_DIM; i += 64) p += ts[i] * g[i];
        #pragma unroll
        for (int m = 32; m >= 1; m >>= 1) p += __shfl_xor(p, m, 64);
        if (lane == 0) logits[e] = p + gb[e];
    }
    __syncthreads();

    if (tid == 0) {
        float lg[NEXP];
        #pragma unroll
        for (int e = 0; e < NEXP; ++e) lg[e] = logits[e];
        float vals[KSEL]; int idx[KSEL];
        #pragma unroll
        for (int k = 0; k < KSEL; ++k) {
            float best = -1e30f; int bi = 0;
            for (int e = 0; e < NEXP; ++e)
                if (lg[e] > best) { best = lg[e]; bi = e; }   // strict > => lowest index on ties
            vals[k] = best; idx[k] = bi; lg[bi] = -1e30f;
        }
        float mx = vals[0], sum = 0.f, ex[KSEL];
        #pragma unroll
        for (int k = 0; k < KSEL; ++k) { ex[k] = expf(vals[k] - mx); sum += ex[k]; }
        float inv = 1.f / sum;
        #pragma unroll
        for (int k = 0; k < KSEL; ++k) {
            topk_idx[t * KSEL + k] = idx[k];
            topk_w[t * KSEL + k] = ex[k] * inv;
            atomicAdd(&counts[idx[k]], 1);
        }
    }
}

// ---------------- Kernel 2: prefix scan ----------------
__global__ void k_scan(const int* __restrict__ counts, int* __restrict__ offsets)
{
    if (threadIdx.x == 0) {
        int acc = 0;
        for (int e = 0; e < NEXP; ++e) { offsets[e] = acc; acc += counts[e]; }
        offsets[NEXP] = acc;
    }
}

// ---------------- Kernel 3: scatter tokens ----------------
__global__ __launch_bounds__(256) void k_place(
    const int* __restrict__ topk_idx, const float* __restrict__ topk_w,
    const int* __restrict__ offsets, int* __restrict__ cursor,
    int* __restrict__ expert_tokens, float* __restrict__ expert_wts)
{
    int t = blockIdx.x * 256 + threadIdx.x;
    if (t >= T_TOK) return;
    #pragma unroll
    for (int k = 0; k < KSEL; ++k) {
        int e = topk_idx[t * KSEL + k];
        int pos = atomicAdd(&cursor[e], 1);
        int slot = offsets[e] + pos;
        expert_tokens[slot] = t;
        expert_wts[slot] = topk_w[t * KSEL + k];
    }
}

// ---------------- Kernel 4: GEMM1 (H->2I) split-fp16 MFMA, 128x(64g+64l) tile, reg-prefetch ----------------
// grid (12, 16, 16), block 256 (4 waves, 2x2). 48 MFMA per K-step per wave-pair region.
__global__ __launch_bounds__(256) void k_gemm1(
    const f16* __restrict__ th, const f16* __restrict__ tl,
    const float* __restrict__ w1, const float* __restrict__ b1,
    const int* __restrict__ expert_tokens, const int* __restrict__ offsets,
    f16* __restrict__ h_h, f16* __restrict__ h_l)
{
    int e = blockIdx.z;
    int beg = offsets[e];
    int cnt = offsets[e + 1] - beg;
    int m0 = blockIdx.y * BM;
    if (m0 >= cnt) return;
    int n0 = blockIdx.x * 64;
    int rows = min(BM, cnt - m0);

    __shared__ f16 A_h[BM][40];
    __shared__ f16 A_l[BM][40];
    __shared__ f16 Bg_h[64][40];
    __shared__ f16 Bg_l[64][40];
    __shared__ f16 Bn_h[64][40];
    __shared__ f16 Bn_l[64][40];
    __shared__ int toks[BM];

    int tid = threadIdx.x;
    int w = tid >> 6, lane = tid & 63;
    if (tid < BM) toks[tid] = (tid < rows) ? expert_tokens[beg + m0 + tid] : -1;
    __syncthreads();

    int arow = tid >> 2, ach = tid & 3;           // A stage: rows arow & arow+64, k-chunk ach*8
    int tokA0 = toks[arow], tokA1 = toks[arow + 64];
    int fr = lane & 15, fg = lane >> 4;
    int wr = w >> 1, wc = w & 1;                  // wave 2x2: rows wr*64.., cols wc*32..

    const float* bgp = w1 + ((size_t)e * H_DIM + w * 8) * TWO_I + n0 + lane;

    half8 z8;
    #pragma unroll
    for (int j = 0; j < 8; ++j) z8[j] = (f16)0.f;

    f32x4 zero4 = {0.f, 0.f, 0.f, 0.f};
    f32x4 accg[4][2], accn[4][2];
    #pragma unroll
    for (int mi = 0; mi < 4; ++mi)
        #pragma unroll
        for (int s = 0; s < 2; ++s) { accg[mi][s] = zero4; accn[mi][s] = zero4; }

    half8 pah0, pal0, pah1, pal1;
    float pbg[8], pbl[8];

#define G1_PRELOAD(KK)                                                          \
    do {                                                                        \
        if (tokA0 >= 0) {                                                       \
            size_t o0 = (size_t)tokA0 * H_DIM + (KK) + ach * 8;                 \
            pah0 = *(const half8*)(th + o0); pal0 = *(const half8*)(tl + o0);   \
        } else { pah0 = z8; pal0 = z8; }                                        \
        if (tokA1 >= 0) {                                                       \
            size_t o1 = (size_t)tokA1 * H_DIM + (KK) + ach * 8;                 \
            pah1 = *(const half8*)(th + o1); pal1 = *(const half8*)(tl + o1);   \
        } else { pah1 = z8; pal1 = z8; }                                        \
        _Pragma("unroll")                                                       \
        for (int j = 0; j < 8; ++j) {                                           \
            pbg[j] = bgp[(size_t)((KK) + j) * TWO_I];                           \
            pbl[j] = bgp[(size_t)((KK) + j) * TWO_I + I_DIM];                   \
        }                                                                       \
    } while (0)

    G1_PRELOAD(0);

    for (int kk = 0; kk < H_DIM; kk += 32) {
        __syncthreads();                       // previous tile consumed
        *(half8*)&A_h[arow][ach * 8] = pah0;
        *(half8*)&A_l[arow][ach * 8] = pal0;
        *(half8*)&A_h[arow + 64][ach * 8] = pah1;
        *(half8*)&A_l[arow + 64][ach * 8] = pal1;
        half8 vgh, vgl, vnh, vnl;
        #pragma unroll
        for (int j = 0; j < 8; ++j) {
            f16 gh = (f16)pbg[j]; vgh[j] = gh; vgl[j] = (f16)(pbg[j] - (float)gh);
            f16 lh = (f16)pbl[j]; vnh[j] = lh; vnl[j] = (f16)(pbl[j] - (float)lh);
        }
        *(half8*)&Bg_h[lane][w * 8] = vgh;
        *(half8*)&Bg_l[lane][w * 8] = vgl;
        *(half8*)&Bn_h[lane][w * 8] = vnh;
        *(half8*)&Bn_l[lane][w * 8] = vnl;
        __syncthreads();                       // tile ready
        if (kk + 32 < H_DIM) G1_PRELOAD(kk + 32);   // overlaps with compute below

        half8 ah[4], al[4];
        #pragma unroll
        for (int mi = 0; mi < 4; ++mi) {
            ah[mi] = *(const half8*)&A_h[wr * 64 + mi * 16 + fr][fg * 8];
            al[mi] = *(const half8*)&A_l[wr * 64 + mi * 16 + fr][fg * 8];
        }
        #pragma unroll
        for (int s = 0; s < 2; ++s) {
            int nb = wc * 32 + s * 16 + fr;
            half8 bgh = *(const half8*)&Bg_h[nb][fg * 8];
            half8 bgl = *(const half8*)&Bg_l[nb][fg * 8];
            half8 bnh = *(const half8*)&Bn_h[nb][fg * 8];
            half8 bnl = *(const half8*)&Bn_l[nb][fg * 8];
            #pragma unroll
            for (int mi = 0; mi < 4; ++mi) {
                accg[mi][s] = __builtin_amdgcn_mfma_f32_16x16x32_f16(ah[mi], bgh, accg[mi][s], 0, 0, 0);
                accg[mi][s] = __builtin_amdgcn_mfma_f32_16x16x32_f16(ah[mi], bgl, accg[mi][s], 0, 0, 0);
                accg[mi][s] = __builtin_amdgcn_mfma_f32_16x16x32_f16(al[mi], bgh, accg[mi][s], 0, 0, 0);
                accn[mi][s] = __builtin_amdgcn_mfma_f32_16x16x32_f16(ah[mi], bnh, accn[mi][s], 0, 0, 0);
                accn[mi][s] = __builtin_amdgcn_mfma_f32_16x16x32_f16(ah[mi], bnl, accn[mi][s], 0, 0, 0);
                accn[mi][s] = __builtin_amdgcn_mfma_f32_16x16x32_f16(al[mi], bnh, accn[mi][s], 0, 0, 0);
            }
        }
    }
#undef G1_PRELOAD

    // epilogue: bias + SwiGLU, split-fp16 store (C/D map m89: col=lane&15, row=(lane>>4)*4+reg)
    const float* b1p = b1 + (size_t)e * TWO_I + n0;
    #pragma unroll
    for (int mi = 0; mi < 4; ++mi) {
        #pragma unroll
        for (int s = 0; s < 2; ++s) {
            #pragma unroll
            for (int r4 = 0; r4 < 4; ++r4) {
                int rt = wr * 64 + mi * 16 + fg * 4 + r4;
                if (rt >= rows) continue;
                int slot = beg + m0 + rt;
                int c = wc * 32 + s * 16 + fr;
                float hg = accg[mi][s][r4] + b1p[c];
                float hl2 = accn[mi][s][r4] + b1p[I_DIM + c];
                hg = fminf(hg, LIMIT);
                hl2 = fminf(fmaxf(hl2, -LIMIT), LIMIT);
                float sg = 1.f / (1.f + expf(-ALPHA * hg));
                float hv = hg * sg * (hl2 + 1.f);
                f16 hh = (f16)hv;
                size_t off = (size_t)slot * I_DIM + n0 + c;
                h_h[off] = hh;
                h_l[off] = (f16)(hv - (float)hh);
            }
        }
    }
}

// ---------------- Kernel 5: GEMM2 (I->H) split-fp16 MFMA, 128x64 tile, reg-prefetch ----------------
// grid (12, 16, 16), block 256 (4 waves stacked in M). 24 MFMA per K-step per wave.
__global__ __launch_bounds__(256) void k_gemm2(
    const f16* __restrict__ h_h, const f16* __restrict__ h_l,
    const float* __restrict__ w2, const float* __restrict__ b2,
    const int* __restrict__ expert_tokens, const float* __restrict__ expert_wts,
    const int* __restrict__ offsets, float* __restrict__ out)
{
    int e = blockIdx.z;
    int beg = offsets[e];
    int cnt = offsets[e + 1] - beg;
    int m0 = blockIdx.y * BM;
    if (m0 >= cnt) return;
    int n0 = blockIdx.x * 64;
    int rows = min(BM, cnt - m0);

    __shared__ f16 A_h[BM][40];
    __shared__ f16 A_l[BM][40];
    __shared__ f16 B_h[64][40];
    __shared__ f16 B_l[64][40];
    __shared__ int   toks[BM];
    __shared__ float wts[BM];

    int tid = threadIdx.x;
    int w = tid >> 6, lane = tid & 63;
    if (tid < BM) {
        bool ok = tid < rows;
        toks[tid] = ok ? expert_tokens[beg + m0 + tid] : -1;
        wts[tid]  = ok ? expert_wts[beg + m0 + tid] : 0.f;
    }
    __syncthreads();

    int arow = tid >> 2, ach = tid & 3;
    bool aok0 = arow < rows, aok1 = (arow + 64) < rows;
    int fr = lane & 15, fg = lane >> 4;
    int r0 = w * 32;

    const float* bp = w2 + ((size_t)e * I_DIM + w * 8) * H_DIM + n0 + lane;

    half8 z8;
    #pragma unroll
    for (int j = 0; j < 8; ++j) z8[j] = (f16)0.f;

    f32x4 zero4 = {0.f, 0.f, 0.f, 0.f};
    f32x4 acc[2][4];
    #pragma unroll
    for (int mi = 0; mi < 2; ++mi)
        #pragma unroll
        for (int s = 0; s < 4; ++s) acc[mi][s] = zero4;

    half8 pah0, pal0, pah1, pal1;
    float pb[8];

#define G2_PRELOAD(KK)                                                          \
    do {                                                                        \
        if (aok0) {                                                             \
            size_t o0 = (size_t)(beg + m0 + arow) * I_DIM + (KK) + ach * 8;     \
            pah0 = *(const half8*)(h_h + o0); pal0 = *(const half8*)(h_l + o0); \
        } else { pah0 = z8; pal0 = z8; }                                        \
        if (aok1) {                                                             \
            size_t o1 = (size_t)(beg + m0 + arow + 64) * I_DIM + (KK) + ach * 8;\
            pah1 = *(const half8*)(h_h + o1); pal1 = *(const half8*)(h_l + o1); \
        } else { pah1 = z8; pal1 = z8; }                                        \
        _Pragma("unroll")                                                       \
        for (int j = 0; j < 8; ++j) pb[j] = bp[(size_t)((KK) + j) * H_DIM];     \
    } while (0)

    G2_PRELOAD(0);

    for (int kk = 0; kk < I_DIM; kk += 32) {
        __syncthreads();
        *(half8*)&A_h[arow][ach * 8] = pah0;
        *(half8*)&A_l[arow][ach * 8] = pal0;
        *(half8*)&A_h[arow + 64][ach * 8] = pah1;
        *(half8*)&A_l[arow + 64][ach * 8] = pal1;
        half8 vbh, vbl;
        #pragma unroll
        for (int j = 0; j < 8; ++j) {
            f16 bh = (f16)pb[j]; vbh[j] = bh; vbl[j] = (f16)(pb[j] - (float)bh);
        }
        *(half8*)&B_h[lane][w * 8] = vbh;
        *(half8*)&B_l[lane][w * 8] = vbl;
        __syncthreads();
        if (kk + 32 < I_DIM) G2_PRELOAD(kk + 32);

        half8 ah[2], al[2];
        #pragma unroll
        for (int mi = 0; mi < 2; ++mi) {
            ah[mi] = *(const half8*)&A_h[r0 + mi * 16 + fr][fg * 8];
            al[mi] = *(const half8*)&A_l[r0 + mi * 16 + fr][fg * 8];
        }
        #pragma unroll
        for (int s = 0; s < 4; ++s) {
            int nb = s * 16 + fr;
            half8 bh = *(const half8*)&B_h[nb][fg * 8];
            half8 bl = *(const half8*)&B_l[nb][fg * 8];
            #pragma unroll
            for (int mi = 0; mi < 2; ++mi) {
                acc[mi][s] = __builtin_amdgcn_mfma_f32_16x16x32_f16(ah[mi], bh, acc[mi][s], 0, 0, 0);
                acc[mi][s] = __builtin_amdgcn_mfma_f32_16x16x32_f16(ah[mi], bl, acc[mi][s], 0, 0, 0);
                acc[mi][s] = __builtin_amdgcn_mfma_f32_16x16x32_f16(al[mi], bh, acc[mi][s], 0, 0, 0);
            }
        }
    }
#undef G2_PRELOAD

    const float* b2p = b2 + (size_t)e * H_DIM + n0;
    #pragma unroll
    for (int mi = 0; mi < 2; ++mi) {
        #pragma unroll
        for (int s = 0; s < 4; ++s) {
            #pragma unroll
            for (int r4 = 0; r4 < 4; ++r4) {
                int rt = r0 + mi * 16 + fg * 4 + r4;
                if (rt >= rows) continue;
                int tok = toks[rt];
                float wgt = wts[rt];
                int c = s * 16 + fr;
                atomicAdd(out + (size_t)tok * H_DIM + n0 + c, wgt * (acc[mi][s][r4] + b2p[c]));
            }
        }
    }
}

// ---------------- launch ----------------
extern "C" void kernel_launch(void* const* d_in, const int* in_sizes, int n_in,
                              void* d_out, int out_size, void* d_ws, size_t ws_size,
                              hipStream_t stream)
{
    const float* x     = (const float*)d_in[0];
    const float* scale = (const float*)d_in[1];
    const float* gw    = (const float*)d_in[2];
    const float* gb    = (const float*)d_in[3];
    const float* w1    = (const float*)d_in[4];
    const float* b1    = (const float*)d_in[5];
    const float* w2    = (const float*)d_in[6];
    const float* b2    = (const float*)d_in[7];
    float* out = (float*)d_out;

    char* ws = (char*)d_ws;
    f16* th  = (f16*)ws;                                   ws += (size_t)T_TOK * H_DIM * 2;
    f16* tl  = (f16*)ws;                                   ws += (size_t)T_TOK * H_DIM * 2;
    f16* h_h = (f16*)ws;                                   ws += (size_t)NSLOT * I_DIM * 2;
    f16* h_l = (f16*)ws;                                   ws += (size_t)NSLOT * I_DIM * 2;
    float* topk_w        = (float*)ws;                     ws += NSLOT * 4;
    float* expert_wts    = (float*)ws;                     ws += NSLOT * 4;
    int*   topk_idx      = (int*)ws;                       ws += NSLOT * 4;
    int*   expert_tokens = (int*)ws;                       ws += NSLOT * 4;
    int*   counts        = (int*)ws;                       ws += NEXP * 4;
    int*   cursor        = (int*)ws;                       ws += NEXP * 4;
    int*   offsets       = (int*)ws;

    hipMemsetAsync(counts, 0, sizeof(int) * 2 * NEXP, stream);  // counts + cursor

    hipLaunchKernelGGL(k_rms_router, dim3(T_TOK), dim3(256), 0, stream,
                       x, scale, gw, gb, th, tl, out, topk_idx, topk_w, counts);
    hipLaunchKernelGGL(k_scan, dim3(1), dim3(64), 0, stream, counts, offsets);
    hipLaunchKernelGGL(k_place, dim3(T_TOK / 256), dim3(256), 0, stream,
                       topk_idx, topk_w, offsets, cursor, expert_tokens, expert_wts);
    hipLaunchKernelGGL(k_gemm1, dim3(I_DIM / 64, T_TOK / BM, NEXP), dim3(256), 0, stream,
                       th, tl, w1, b1, expert_tokens, offsets, h_h, h_l);
    hipLaunchKernelGGL(k_gemm2, dim3(H_DIM / 64, T_TOK / BM, NEXP), dim3(256), 0, stream,
                       h_h, h_l, w2, b2, expert_tokens, expert_wts, offsets, out);
}

// Round 8
// 306.092 us; speedup vs baseline: 1.7673x; 1.5385x over previous
//
#include <hip/hip_runtime.h>
#include <hip/hip_bf16.h>
#include <cstddef>

#define T_TOK 2048
#define H_DIM 768
#define NEXP 16
#define KSEL 4
#define I_DIM 768
#define TWO_I 1536
#define NSLOT (T_TOK*KSEL)
#define ALPHA 1.702f
#define LIMIT 7.0f
#define EPS_RMS 1e-5f
#define BM 128

typedef _Float16 f16;
typedef _Float16 half8 __attribute__((ext_vector_type(8)));
typedef float f32x4 __attribute__((ext_vector_type(4)));

// ---------------- Kernel 1: RMSNorm + router (fp32) + residual init ----------------
__global__ __launch_bounds__(256) void k_rms_router(
    const float* __restrict__ x, const float* __restrict__ scale,
    const float* __restrict__ gw, const float* __restrict__ gb,
    f16* __restrict__ th, float* __restrict__ out,
    int* __restrict__ topk_idx, float* __restrict__ topk_w)
{
    int t = blockIdx.x;
    int tid = threadIdx.x;
    int lane = tid & 63, wid = tid >> 6;
    __shared__ float ts[H_DIM];
    __shared__ float red[8];
    __shared__ float logits[NEXP];

    const float* xr = x + (size_t)t * H_DIM;
    float v0 = xr[tid], v1 = xr[tid + 256], v2 = xr[tid + 512];
    float ss = v0*v0 + v1*v1 + v2*v2;
    #pragma unroll
    for (int m = 32; m >= 1; m >>= 1) ss += __shfl_xor(ss, m, 64);
    if (lane == 0) red[wid] = ss;
    __syncthreads();
    if (tid == 0) {
        float tot = red[0] + red[1] + red[2] + red[3];
        red[4] = rsqrtf(tot / (float)H_DIM + EPS_RMS);
    }
    __syncthreads();
    float rinv = red[4];
    float t0 = v0 * rinv * scale[tid];
    float t1 = v1 * rinv * scale[tid + 256];
    float t2 = v2 * rinv * scale[tid + 512];
    ts[tid] = t0; ts[tid + 256] = t1; ts[tid + 512] = t2;
    size_t base = (size_t)t * H_DIM;
    th[base + tid] = (f16)t0;
    th[base + tid + 256] = (f16)t1;
    th[base + tid + 512] = (f16)t2;
    float* op = out + base;
    op[tid] = v0; op[tid + 256] = v1; op[tid + 512] = v2;
    __syncthreads();

    #pragma unroll
    for (int ee = 0; ee < 4; ++ee) {
        int e = wid * 4 + ee;
        const float* g = gw + (size_t)e * H_DIM;
        float p = 0.f;
        for (int i = lane; i < H_DIM; i += 64) p += ts[i] * g[i];
        #pragma unroll
        for (int m = 32; m >= 1; m >>= 1) p += __shfl_xor(p, m, 64);
        if (lane == 0) logits[e] = p + gb[e];
    }
    __syncthreads();

    if (tid == 0) {
        float lg[NEXP];
        #pragma unroll
        for (int e = 0; e < NEXP; ++e) lg[e] = logits[e];
        float vals[KSEL]; int idx[KSEL];
        #pragma unroll
        for (int k = 0; k < KSEL; ++k) {
            float best = -1e30f; int bi = 0;
            for (int e = 0; e < NEXP; ++e)
                if (lg[e] > best) { best = lg[e]; bi = e; }   // strict > => lowest index on ties
            vals[k] = best; idx[k] = bi; lg[bi] = -1e30f;
        }
        float mx = vals[0], sum = 0.f, ex[KSEL];
        #pragma unroll
        for (int k = 0; k < KSEL; ++k) { ex[k] = expf(vals[k] - mx); sum += ex[k]; }
        float inv = 1.f / sum;
        #pragma unroll
        for (int k = 0; k < KSEL; ++k) {
            topk_idx[t * KSEL + k] = idx[k];
            topk_w[t * KSEL + k] = ex[k] * inv;   // softmax/K * K cancels
        }
    }
}

// ---------------- Kernel 2a: per-expert count (no atomics) ----------------
__global__ __launch_bounds__(256) void k_count(
    const int* __restrict__ topk_idx, int* __restrict__ counts)
{
    int e = blockIdx.x;
    int tid = threadIdx.x;
    int c = 0;
    for (int i = tid; i < NSLOT; i += 256) c += (topk_idx[i] == e) ? 1 : 0;
    #pragma unroll
    for (int m = 32; m >= 1; m >>= 1) c += __shfl_xor(c, m, 64);
    __shared__ int r[4];
    if ((tid & 63) == 0) r[tid >> 6] = c;
    __syncthreads();
    if (tid == 0) counts[e] = r[0] + r[1] + r[2] + r[3];
}

// ---------------- Kernel 2b: prefix scan ----------------
__global__ void k_scan(const int* __restrict__ counts, int* __restrict__ offsets)
{
    if (threadIdx.x == 0) {
        int acc = 0;
        for (int e = 0; e < NEXP; ++e) { offsets[e] = acc; acc += counts[e]; }
        offsets[NEXP] = acc;
    }
}

// ---------------- Kernel 3: rank-based scatter (no atomics) ----------------
// block e scans all NSLOT entries; stable rank via per-thread chunks + LDS prefix.
__global__ __launch_bounds__(256) void k_place(
    const int* __restrict__ topk_idx, const float* __restrict__ topk_w,
    const int* __restrict__ offsets,
    int* __restrict__ expert_tokens, float* __restrict__ expert_wts)
{
    int e = blockIdx.x;
    int tid = threadIdx.x;
    __shared__ int ps[256];
    int base = tid * 32;                       // NSLOT = 256*32
    int c = 0;
    #pragma unroll 8
    for (int j = 0; j < 32; ++j) c += (topk_idx[base + j] == e) ? 1 : 0;
    ps[tid] = c;
    __syncthreads();
    if (tid == 0) {
        int run = 0;
        for (int i = 0; i < 256; ++i) { int v = ps[i]; ps[i] = run; run += v; }
    }
    __syncthreads();
    int slot = offsets[e] + ps[tid];
    for (int j = 0; j < 32; ++j) {
        int i = base + j;
        if (topk_idx[i] == e) {
            expert_tokens[slot] = i >> 2;      // i = t*KSEL + k
            expert_wts[slot] = topk_w[i];
            ++slot;
        }
    }
}

// ---------------- Kernel 4: GEMM1 (H->2I) fp16 MFMA, 128x(64g+64l) tile, reg-prefetch ----------------
// grid (12, 16, 16), block 256 (4 waves, 2x2 -> each wave 64 rows x 32 cols of both halves).
__global__ __launch_bounds__(256) void k_gemm1(
    const f16* __restrict__ th, const float* __restrict__ w1,
    const float* __restrict__ b1,
    const int* __restrict__ expert_tokens, const int* __restrict__ offsets,
    f16* __restrict__ h_buf)
{
    int e = blockIdx.z;
    int beg = offsets[e];
    int cnt = offsets[e + 1] - beg;
    int m0 = blockIdx.y * BM;
    if (m0 >= cnt) return;
    int n0 = blockIdx.x * 64;
    int rows = min(BM, cnt - m0);

    __shared__ f16 A_h[BM][40];
    __shared__ f16 Bg_h[64][40];
    __shared__ f16 Bn_h[64][40];
    __shared__ int toks[BM];

    int tid = threadIdx.x;
    int w = tid >> 6, lane = tid & 63;
    if (tid < BM) toks[tid] = (tid < rows) ? expert_tokens[beg + m0 + tid] : -1;
    __syncthreads();

    int arow = tid >> 2, ach = tid & 3;
    int tokA0 = toks[arow], tokA1 = toks[arow + 64];
    int fr = lane & 15, fg = lane >> 4;
    int wr = w >> 1, wc = w & 1;

    const float* bgp = w1 + ((size_t)e * H_DIM + w * 8) * TWO_I + n0 + lane;

    half8 z8;
    #pragma unroll
    for (int j = 0; j < 8; ++j) z8[j] = (f16)0.f;

    f32x4 zero4 = {0.f, 0.f, 0.f, 0.f};
    f32x4 accg[4][2], accn[4][2];
    #pragma unroll
    for (int mi = 0; mi < 4; ++mi)
        #pragma unroll
        for (int s = 0; s < 2; ++s) { accg[mi][s] = zero4; accn[mi][s] = zero4; }

    half8 pah0, pah1;
    float pbg[8], pbn[8];

#define G1_PRELOAD(KK)                                                          \
    do {                                                                        \
        pah0 = (tokA0 >= 0) ? *(const half8*)(th + (size_t)tokA0 * H_DIM + (KK) + ach * 8) : z8; \
        pah1 = (tokA1 >= 0) ? *(const half8*)(th + (size_t)tokA1 * H_DIM + (KK) + ach * 8) : z8; \
        _Pragma("unroll")                                                       \
        for (int j = 0; j < 8; ++j) {                                           \
            pbg[j] = bgp[(size_t)((KK) + j) * TWO_I];                           \
            pbn[j] = bgp[(size_t)((KK) + j) * TWO_I + I_DIM];                   \
        }                                                                       \
    } while (0)

    G1_PRELOAD(0);

    for (int kk = 0; kk < H_DIM; kk += 32) {
        __syncthreads();                       // previous tile consumed
        *(half8*)&A_h[arow][ach * 8] = pah0;
        *(half8*)&A_h[arow + 64][ach * 8] = pah1;
        half8 vgh, vnh;
        #pragma unroll
        for (int j = 0; j < 8; ++j) {
            vgh[j] = (f16)pbg[j];
            vnh[j] = (f16)pbn[j];
        }
        *(half8*)&Bg_h[lane][w * 8] = vgh;
        *(half8*)&Bn_h[lane][w * 8] = vnh;
        __syncthreads();                       // tile ready
        if (kk + 32 < H_DIM) G1_PRELOAD(kk + 32);   // overlaps compute

        half8 ah[4];
        #pragma unroll
        for (int mi = 0; mi < 4; ++mi)
            ah[mi] = *(const half8*)&A_h[wr * 64 + mi * 16 + fr][fg * 8];
        #pragma unroll
        for (int s = 0; s < 2; ++s) {
            int nb = wc * 32 + s * 16 + fr;
            half8 bgh = *(const half8*)&Bg_h[nb][fg * 8];
            half8 bnh = *(const half8*)&Bn_h[nb][fg * 8];
            #pragma unroll
            for (int mi = 0; mi < 4; ++mi) {
                accg[mi][s] = __builtin_amdgcn_mfma_f32_16x16x32_f16(ah[mi], bgh, accg[mi][s], 0, 0, 0);
                accn[mi][s] = __builtin_amdgcn_mfma_f32_16x16x32_f16(ah[mi], bnh, accn[mi][s], 0, 0, 0);
            }
        }
    }
#undef G1_PRELOAD

    // epilogue: bias + SwiGLU, fp16 store (C/D map m89: col=lane&15, row=(lane>>4)*4+reg)
    const float* b1p = b1 + (size_t)e * TWO_I + n0;
    #pragma unroll
    for (int mi = 0; mi < 4; ++mi) {
        #pragma unroll
        for (int s = 0; s < 2; ++s) {
            #pragma unroll
            for (int r4 = 0; r4 < 4; ++r4) {
                int rt = wr * 64 + mi * 16 + fg * 4 + r4;
                if (rt >= rows) continue;
                int slot = beg + m0 + rt;
                int c = wc * 32 + s * 16 + fr;
                float hg = accg[mi][s][r4] + b1p[c];
                float hl2 = accn[mi][s][r4] + b1p[I_DIM + c];
                hg = fminf(hg, LIMIT);
                hl2 = fminf(fmaxf(hl2, -LIMIT), LIMIT);
                float sg = 1.f / (1.f + expf(-ALPHA * hg));
                h_buf[(size_t)slot * I_DIM + n0 + c] = (f16)(hg * sg * (hl2 + 1.f));
            }
        }
    }
}

// ---------------- Kernel 5: GEMM2 (I->H) fp16 MFMA, 128x64 tile, reg-prefetch ----------------
__global__ __launch_bounds__(256) void k_gemm2(
    const f16* __restrict__ h_buf, const float* __restrict__ w2,
    const float* __restrict__ b2,
    const int* __restrict__ expert_tokens, const float* __restrict__ expert_wts,
    const int* __restrict__ offsets, float* __restrict__ out)
{
    int e = blockIdx.z;
    int beg = offsets[e];
    int cnt = offsets[e + 1] - beg;
    int m0 = blockIdx.y * BM;
    if (m0 >= cnt) return;
    int n0 = blockIdx.x * 64;
    int rows = min(BM, cnt - m0);

    __shared__ f16 A_h[BM][40];
    __shared__ f16 B_h[64][40];
    __shared__ int   toks[BM];
    __shared__ float wts[BM];

    int tid = threadIdx.x;
    int w = tid >> 6, lane = tid & 63;
    if (tid < BM) {
        bool ok = tid < rows;
        toks[tid] = ok ? expert_tokens[beg + m0 + tid] : -1;
        wts[tid]  = ok ? expert_wts[beg + m0 + tid] : 0.f;
    }
    __syncthreads();

    int arow = tid >> 2, ach = tid & 3;
    bool aok0 = arow < rows, aok1 = (arow + 64) < rows;
    int fr = lane & 15, fg = lane >> 4;
    int r0 = w * 32;

    const float* bp = w2 + ((size_t)e * I_DIM + w * 8) * H_DIM + n0 + lane;

    half8 z8;
    #pragma unroll
    for (int j = 0; j < 8; ++j) z8[j] = (f16)0.f;

    f32x4 zero4 = {0.f, 0.f, 0.f, 0.f};
    f32x4 acc[2][4];
    #pragma unroll
    for (int mi = 0; mi < 2; ++mi)
        #pragma unroll
        for (int s = 0; s < 4; ++s) acc[mi][s] = zero4;

    half8 pah0, pah1;
    float pb[8];

#define G2_PRELOAD(KK)                                                          \
    do {                                                                        \
        pah0 = aok0 ? *(const half8*)(h_buf + (size_t)(beg + m0 + arow) * I_DIM + (KK) + ach * 8) : z8; \
        pah1 = aok1 ? *(const half8*)(h_buf + (size_t)(beg + m0 + arow + 64) * I_DIM + (KK) + ach * 8) : z8; \
        _Pragma("unroll")                                                       \
        for (int j = 0; j < 8; ++j) pb[j] = bp[(size_t)((KK) + j) * H_DIM];     \
    } while (0)

    G2_PRELOAD(0);

    for (int kk = 0; kk < I_DIM; kk += 32) {
        __syncthreads();
        *(half8*)&A_h[arow][ach * 8] = pah0;
        *(half8*)&A_h[arow + 64][ach * 8] = pah1;
        half8 vbh;
        #pragma unroll
        for (int j = 0; j < 8; ++j) vbh[j] = (f16)pb[j];
        *(half8*)&B_h[lane][w * 8] = vbh;
        __syncthreads();
        if (kk + 32 < I_DIM) G2_PRELOAD(kk + 32);

        half8 ah[2];
        #pragma unroll
        for (int mi = 0; mi < 2; ++mi)
            ah[mi] = *(const half8*)&A_h[r0 + mi * 16 + fr][fg * 8];
        #pragma unroll
        for (int s = 0; s < 4; ++s) {
            half8 bh = *(const half8*)&B_h[s * 16 + fr][fg * 8];
            #pragma unroll
            for (int mi = 0; mi < 2; ++mi)
                acc[mi][s] = __builtin_amdgcn_mfma_f32_16x16x32_f16(ah[mi], bh, acc[mi][s], 0, 0, 0);
        }
    }
#undef G2_PRELOAD

    const float* b2p = b2 + (size_t)e * H_DIM + n0;
    #pragma unroll
    for (int mi = 0; mi < 2; ++mi) {
        #pragma unroll
        for (int s = 0; s < 4; ++s) {
            #pragma unroll
            for (int r4 = 0; r4 < 4; ++r4) {
                int rt = r0 + mi * 16 + fg * 4 + r4;
                if (rt >= rows) continue;
                int tok = toks[rt];
                float wgt = wts[rt];
                int c = s * 16 + fr;
                atomicAdd(out + (size_t)tok * H_DIM + n0 + c, wgt * (acc[mi][s][r4] + b2p[c]));
            }
        }
    }
}

// ---------------- launch ----------------
extern "C" void kernel_launch(void* const* d_in, const int* in_sizes, int n_in,
                              void* d_out, int out_size, void* d_ws, size_t ws_size,
                              hipStream_t stream)
{
    const float* x     = (const float*)d_in[0];
    const float* scale = (const float*)d_in[1];
    const float* gw    = (const float*)d_in[2];
    const float* gb    = (const float*)d_in[3];
    const float* w1    = (const float*)d_in[4];
    const float* b1    = (const float*)d_in[5];
    const float* w2    = (const float*)d_in[6];
    const float* b2    = (const float*)d_in[7];
    float* out = (float*)d_out;

    char* ws = (char*)d_ws;
    f16* th    = (f16*)ws;                                 ws += (size_t)T_TOK * H_DIM * 2;
    f16* h_buf = (f16*)ws;                                 ws += (size_t)NSLOT * I_DIM * 2;
    float* topk_w        = (float*)ws;                     ws += NSLOT * 4;
    float* expert_wts    = (float*)ws;                     ws += NSLOT * 4;
    int*   topk_idx      = (int*)ws;                       ws += NSLOT * 4;
    int*   expert_tokens = (int*)ws;                       ws += NSLOT * 4;
    int*   counts        = (int*)ws;                       ws += NEXP * 4;
    int*   offsets       = (int*)ws;

    hipLaunchKernelGGL(k_rms_router, dim3(T_TOK), dim3(256), 0, stream,
                       x, scale, gw, gb, th, out, topk_idx, topk_w);
    hipLaunchKernelGGL(k_count, dim3(NEXP), dim3(256), 0, stream, topk_idx, counts);
    hipLaunchKernelGGL(k_scan, dim3(1), dim3(64), 0, stream, counts, offsets);
    hipLaunchKernelGGL(k_place, dim3(NEXP), dim3(256), 0, stream,
                       topk_idx, topk_w, offsets, expert_tokens, expert_wts);
    hipLaunchKernelGGL(k_gemm1, dim3(I_DIM / 64, T_TOK / BM, NEXP), dim3(256), 0, stream,
                       th, w1, b1, expert_tokens, offsets, h_buf);
    hipLaunchKernelGGL(k_gemm2, dim3(H_DIM / 64, T_TOK / BM, NEXP), dim3(256), 0, stream,
                       h_buf, w2, b2, expert_tokens, expert_wts, offsets, out);
}